// Round 7
// baseline (253.554 us; speedup 1.0000x reference)
//
#include <hip/hip_runtime.h>

typedef _Float16 f16;
typedef _Float16 f16x8 __attribute__((ext_vector_type(8)));
typedef _Float16 f16x4 __attribute__((ext_vector_type(4)));
typedef _Float16 f16x2 __attribute__((ext_vector_type(2)));
typedef float f32x4 __attribute__((ext_vector_type(4)));

#define L2E 1.44269504088896f

typedef __attribute__((address_space(1))) void GV;
typedef __attribute__((address_space(3))) void LV;
__device__ __forceinline__ void gl2lds(const void* gp, void* lp) {
    __builtin_amdgcn_global_load_lds((GV*)gp, (LV*)lp, 16, 0, 0);
}

// ---------------- W convert fp32 -> f16 ----------------
__global__ void k_wcvt(const float* __restrict__ w, f16* __restrict__ wh) {
    int i = (blockIdx.x * 256 + threadIdx.x) * 4;
    float4 v = *(const float4*)(w + i);
    f16x4 o = { (f16)v.x, (f16)v.y, (f16)v.z, (f16)v.w };
    *(f16x4*)(wh + i) = o;
}

// ------- depthwise 3x3 conv + transpose [B,C,N]->[B,N,C] + f16 cast -------
__launch_bounds__(256)
__global__ void k_prep(const float* __restrict__ x, const float* __restrict__ wdw,
                       const float* __restrict__ bdw,
                       f16* __restrict__ xt, f16* __restrict__ rbt) {
    int ht = blockIdx.x, ct = blockIdx.y, b = blockIdx.z;
    __shared__ float xs[64 * 129];
    int t = threadIdx.x;
    int h0 = ht * 2;
#pragma unroll
    for (int i = 0; i < 8; ++i) {
        int idx = t + i * 256;
        int cl = idx >> 5, col4 = idx & 31;
        int hh = h0 - 1 + (col4 >> 3);
        int wq = (col4 & 7) * 4;
        float4 v = make_float4(0.f, 0.f, 0.f, 0.f);
        if (hh >= 0 && hh < 32)
            v = *(const float4*)(x + (size_t)(b * 384 + ct * 64 + cl) * 1024 + hh * 32 + wq);
        int base = cl * 129 + col4 * 4;
        xs[base] = v.x; xs[base + 1] = v.y; xs[base + 2] = v.z; xs[base + 3] = v.w;
    }
    __syncthreads();
    int cl = t & 63;
    int c = ct * 64 + cl;
    float wd[9];
#pragma unroll
    for (int k = 0; k < 9; ++k) wd[k] = wdw[c * 9 + k];
    float bd = bdw[c];
    const float* row = &xs[cl * 129];
    int nb = (t >> 6) * 16;
#pragma unroll
    for (int i = 0; i < 16; ++i) {
        int nl = nb + i;
        int hh = nl >> 5, ww = nl & 31;
        int lx = hh + 1;
        float acc = bd;
#pragma unroll
        for (int dh = -1; dh <= 1; ++dh) {
#pragma unroll
            for (int dw = -1; dw <= 1; ++dw) {
                int w2 = ww + dw;
                if (w2 >= 0 && w2 <= 31)
                    acc += wd[(dh + 1) * 3 + (dw + 1)] * row[(lx + dh) * 32 + w2];
            }
        }
        float xc = row[lx * 32 + ww];
        size_t at = ((size_t)(b * 1024) + h0 * 32 + nl) * 384 + c;
        rbt[at] = (f16)acc;
        xt[at] = (f16)xc;
    }
}

// ---------------- QKV GEMM (unchanged, known-good) ----------------
__launch_bounds__(256, 2)
__global__ void k_gemm1(const f16* __restrict__ xt, const f16* __restrict__ wh,
                        const float* __restrict__ bias, const f16* __restrict__ rbt,
                        f16* __restrict__ qo, f16* __restrict__ krb, f16* __restrict__ vt) {
    __shared__ f16 As[128 * 64];
    __shared__ f16 Bs[128 * 64];
    int bm = blockIdx.x, bn = blockIdx.y, b = blockIdx.z;
    int t = threadIdx.x, lane = t & 63, wv = t >> 6;
    int wm = wv >> 1, wn = wv & 1;
    f32x4 acc[4][4] = {};
    const char* xbase = (const char*)(xt + (size_t)(b * 1024 + bm * 128) * 384);
    const char* wbase = (const char*)(wh + (size_t)(bn * 128) * 384);
    const bool vmode = (bn >= 6);
    int soff[4];
#pragma unroll
    for (int i = 0; i < 4; ++i) {
        int idx = i * 256 + t;
        int r = idx >> 3, cg = idx & 7;
        soff[i] = r * 768 + ((cg ^ (r & 7)) << 4);
    }
    for (int kc = 0; kc < 6; ++kc) {
        __syncthreads();
#pragma unroll
        for (int i = 0; i < 4; ++i) {
            gl2lds(xbase + kc * 128 + soff[i], (char*)As + (i * 256 + wv * 64) * 16);
            gl2lds(wbase + kc * 128 + soff[i], (char*)Bs + (i * 256 + wv * 64) * 16);
        }
        __syncthreads();
#pragma unroll
        for (int j = 0; j < 2; ++j) {
            f16x8 af[4], bf[4];
#pragma unroll
            for (int mr = 0; mr < 4; ++mr) {
                int rowi = wm * 64 + mr * 16 + (lane & 15);
                af[mr] = *(const f16x8*)((const char*)As + rowi * 128 +
                         ((j * 64 + (lane >> 4) * 16) ^ ((rowi & 7) << 4)));
            }
#pragma unroll
            for (int nr = 0; nr < 4; ++nr) {
                int rowi = wn * 64 + nr * 16 + (lane & 15);
                bf[nr] = *(const f16x8*)((const char*)Bs + rowi * 128 +
                         ((j * 64 + (lane >> 4) * 16) ^ ((rowi & 7) << 4)));
            }
            __builtin_amdgcn_s_setprio(1);
            if (!vmode) {
#pragma unroll
                for (int mr = 0; mr < 4; ++mr)
#pragma unroll
                    for (int nr = 0; nr < 4; ++nr)
                        acc[mr][nr] = __builtin_amdgcn_mfma_f32_16x16x32_f16(af[mr], bf[nr], acc[mr][nr], 0, 0, 0);
            } else {
#pragma unroll
                for (int mr = 0; mr < 4; ++mr)
#pragma unroll
                    for (int nr = 0; nr < 4; ++nr)
                        acc[mr][nr] = __builtin_amdgcn_mfma_f32_16x16x32_f16(bf[nr], af[mr], acc[mr][nr], 0, 0, 0);
            }
            __builtin_amdgcn_s_setprio(0);
        }
    }
    int o0 = bn * 128;
    if (!vmode) {
#pragma unroll
        for (int nr = 0; nr < 4; ++nr) {
            int o = o0 + wn * 64 + nr * 16 + (lane & 15);
            float bs = bias[o];
#pragma unroll
            for (int mr = 0; mr < 4; ++mr) {
                int n_l = wm * 64 + mr * 16 + ((lane >> 4) << 2);
#pragma unroll
                for (int r = 0; r < 4; ++r) {
                    int n_sp = bm * 128 + n_l + r;
                    size_t at = (size_t)(b * 1024 + n_sp) * 384;
                    float vv = acc[mr][nr][r] + bs;
                    if (o < 384) qo[at + o] = (f16)vv;
                    else krb[at + (o - 384)] = (f16)(vv + (float)rbt[at + (o - 384)]);
                }
            }
        }
    } else {
#pragma unroll
        for (int nr = 0; nr < 4; ++nr) {
#pragma unroll
            for (int mr = 0; mr < 4; ++mr) {
                int n_sp = bm * 128 + wm * 64 + mr * 16 + (lane & 15);
                int o_l = wn * 64 + nr * 16 + ((lane >> 4) << 2);
#pragma unroll
                for (int r = 0; r < 4; ++r) {
                    float vv = acc[mr][nr][r] + bias[o0 + o_l + r];
                    vt[(size_t)(b * 384 + (o0 - 768) + o_l + r) * 1024 + n_sp] = (f16)vv;
                }
            }
        }
    }
}

// -------- flash v5: QBLK=32, kv-halves, K in LDS (single buf), V direct from L2 --------
// grid: (qt=32, b=16) = 512 blocks (2/CU), 256 threads (4 waves).
// Wave (h, qw): h = kv-half, qw = q-group. KVBLK=32, 16 iters/half.
// LDS: Ks[2 halves][32 kv][768 B] = 48 KB static. No V staging.
__launch_bounds__(256, 2)
__global__ void k_flash5(const f16* __restrict__ q, const f16* __restrict__ krb,
                         const f16* __restrict__ vt, float* __restrict__ out) {
    __shared__ char smem[49152];
    __shared__ float mlb[32][2];
    int qt = blockIdx.x, b = blockIdx.y;
    int t = threadIdx.x, lane = t & 63, wv = t >> 6;
    int g = lane >> 4, ln = lane & 15;
    int h = wv >> 1, qw = wv & 1;
    char* Ks = smem + h * 24576;

    // Q in regs as QK B-fragment (col=q=ln, k = g*8+e per 32-c chunk)
    f16x8 qf[12];
    {
        const f16* qb = q + (size_t)(b * 1024 + qt * 32 + qw * 16 + ln) * 384 + g * 8;
#pragma unroll
        for (int kc = 0; kc < 12; ++kc) qf[kc] = *(const f16x8*)(qb + kc * 32);
    }

    // K staging offsets (pre-swizzled global source; linear LDS dest)
    int tp = t & 127;
    int koff[12];
#pragma unroll
    for (int i = 0; i < 12; ++i) {
        int idx = i * 128 + tp;                 // 1536 granules = 32 rows x 48
        int r = idx / 48, c = idx - r * 48;
        koff[i] = r * 768 + ((c ^ (r & 7)) << 4);
    }
    const char* kbase = (const char*)krb + (size_t)b * 786432 + (size_t)h * 393216;
    const f16* vbase = vt + (size_t)b * 384 * 1024 + h * 512;

    // prologue: stage K[0]
#pragma unroll
    for (int i = 0; i < 12; ++i)
        gl2lds(kbase + koff[i], Ks + (i * 128 + qw * 64) * 16);

    f32x4 oa[24];
#pragma unroll
    for (int i = 0; i < 24; ++i) oa[i] = (f32x4){0.f, 0.f, 0.f, 0.f};
    float m_run = -1e30f, l_run = 0.f;
    int src0 = 2 * (g & 1) * 16 + ln, src1 = src0 + 16;
    bool gh = (g >= 2);

    for (int kt = 0; kt < 16; ++kt) {
        __syncthreads();               // K[kt] landed
        // QK^T swapped: S^T[kv][q], kv = nr*16 + g*4 + r, q = ln
        f32x4 st[2] = {};
        __builtin_amdgcn_s_setprio(1);
#pragma unroll
        for (int kc = 0; kc < 12; ++kc) {
#pragma unroll
            for (int nr = 0; nr < 2; ++nr) {
                int kvr = nr * 16 + ln;
                f16x8 kf = *(const f16x8*)(Ks + kvr * 768 +
                            ((kc * 64 + g * 16) ^ ((kvr & 7) << 4)));
                st[nr] = __builtin_amdgcn_mfma_f32_16x16x32_f16(kf, qf[kc], st[nr], 0, 0, 0);
            }
        }
        __builtin_amdgcn_s_setprio(0);
        __syncthreads();               // Ks reads complete
        if (kt < 15) {                 // stage K[kt+1]; latency hides under softmax+PV
#pragma unroll
            for (int i = 0; i < 12; ++i)
                gl2lds(kbase + (kt + 1) * 24576 + koff[i], Ks + (i * 128 + qw * 64) * 16);
        }

        // register online softmax (per-lane q = ln), T13 defer-rescale
        float mx = st[0][0];
#pragma unroll
        for (int nr = 0; nr < 2; ++nr)
#pragma unroll
            for (int r = 0; r < 4; ++r) mx = fmaxf(mx, st[nr][r]);
        mx = fmaxf(mx, __shfl_xor(mx, 16));
        mx = fmaxf(mx, __shfl_xor(mx, 32));
        float mn;
        if (__all(mx <= m_run + 8.0f)) {
            mn = m_run;
        } else {
            mn = fmaxf(m_run, mx);
            float sc = exp2f((m_run - mn) * L2E);
            m_run = mn;
            l_run *= sc;
#pragma unroll
            for (int i = 0; i < 24; ++i) oa[i] *= sc;
        }
        float pv[2][4], ls = 0.f;
#pragma unroll
        for (int nr = 0; nr < 2; ++nr)
#pragma unroll
            for (int r = 0; r < 4; ++r) {
                float p = exp2f((st[nr][r] - mn) * L2E);
                pv[nr][r] = p;
                ls += p;
            }
        ls += __shfl_xor(ls, 16);
        ls += __shfl_xor(ls, 32);
        l_run += ls;

        // pack P^T to f16 pairs, shuffle into PV B-fragment (k=kv local, col=q)
        int pk[4];
#pragma unroll
        for (int nr = 0; nr < 2; ++nr)
#pragma unroll
            for (int hh = 0; hh < 2; ++hh) {
                f16x2 w2 = { (f16)pv[nr][2 * hh], (f16)pv[nr][2 * hh + 1] };
                pk[nr * 2 + hh] = __builtin_bit_cast(int, w2);
            }
        f16x8 pb;
        {
            int a0 = __shfl(pk[0], src0);
            int a1 = __shfl(pk[1], src0);
            int a2 = __shfl(pk[2], src0);
            int a3 = __shfl(pk[3], src0);
            int b0 = __shfl(pk[0], src1);
            int b1 = __shfl(pk[1], src1);
            int b2 = __shfl(pk[2], src1);
            int b3 = __shfl(pk[3], src1);
            union { int w[4]; f16x8 v; } u;
            u.w[0] = gh ? a2 : a0;
            u.w[1] = gh ? a3 : a1;
            u.w[2] = gh ? b2 : b0;
            u.w[3] = gh ? b3 : b1;
            pb = u.v;
        }

        // PV: O^T[c][q] += V^T x P^T; V fragments straight from global (L2/L1-resident)
        const f16* vrow = vbase + kt * 32 + g * 8;
        __builtin_amdgcn_s_setprio(1);
#pragma unroll
        for (int nr2 = 0; nr2 < 24; ++nr2) {
            int cr = nr2 * 16 + ln;
            f16x8 vf = *(const f16x8*)(vrow + (size_t)cr * 1024);
            oa[nr2] = __builtin_amdgcn_mfma_f32_16x16x32_f16(vf, pb, oa[nr2], 0, 0, 0);
        }
        __builtin_amdgcn_s_setprio(0);
    }

    // ---- combine halves via LDS, then store out[b][c][n] ----
    __syncthreads();                   // Ks free for reuse
    float* ob = (float*)smem;          // [384 c][32 q] f32 = 48 KB
    if (h == 1) {
        if (g == 0) {
            mlb[qw * 16 + ln][0] = m_run;
            mlb[qw * 16 + ln][1] = l_run;
        }
#pragma unroll
        for (int nr2 = 0; nr2 < 24; ++nr2)
#pragma unroll
            for (int r = 0; r < 4; ++r)
                ob[(nr2 * 16 + g * 4 + r) * 32 + qw * 16 + ln] = oa[nr2][r];
    }
    __syncthreads();
    if (h == 0) {
        int qq = qw * 16 + ln;
        float mB = mlb[qq][0], lB = mlb[qq][1];
        float M = fmaxf(m_run, mB);
        float eA = exp2f((m_run - M) * L2E);
        float eB = exp2f((mB - M) * L2E);
        float linv = 1.0f / (l_run * eA + lB * eB);
#pragma unroll
        for (int nr2 = 0; nr2 < 24; ++nr2) {
#pragma unroll
            for (int r = 0; r < 4; ++r) {
                int c = nr2 * 16 + g * 4 + r;
                out[(size_t)(b * 384 + c) * 1024 + qt * 32 + qq] =
                    (oa[nr2][r] * eA + ob[c * 32 + qq] * eB) * linv;
            }
        }
    }
}

extern "C" void kernel_launch(void* const* d_in, const int* in_sizes, int n_in,
                              void* d_out, int out_size, void* d_ws, size_t ws_size,
                              hipStream_t stream) {
    const float* x     = (const float*)d_in[0];
    const float* w_qkv = (const float*)d_in[1];
    const float* b_qkv = (const float*)d_in[2];
    const float* w_dw  = (const float*)d_in[3];
    const float* b_dw  = (const float*)d_in[4];
    float* out = (float*)d_out;
    char* ws = (char*)d_ws;
    const size_t SZ = (size_t)16 * 1024 * 384 * 2;
    f16* xt  = (f16*)(ws);
    f16* rbt = (f16*)(ws + SZ);
    f16* qo  = (f16*)(ws + 2 * SZ);
    f16* krb = (f16*)(ws + 3 * SZ);
    f16* vt  = (f16*)(ws + 4 * SZ);
    f16* wh  = (f16*)(ws + 5 * SZ);

    k_wcvt<<<432, 256, 0, stream>>>(w_qkv, wh);
    k_prep<<<dim3(16, 6, 16), 256, 0, stream>>>(x, w_dw, b_dw, xt, rbt);
    k_gemm1<<<dim3(8, 9, 16), 256, 0, stream>>>(xt, wh, b_qkv, rbt, qo, krb, vt);
    k_flash5<<<dim3(32, 16), 256, 0, stream>>>(qo, krb, vt, out);
}

// Round 8
// 210.389 us; speedup vs baseline: 1.2052x; 1.2052x over previous
//
#include <hip/hip_runtime.h>

typedef _Float16 f16;
typedef _Float16 f16x8 __attribute__((ext_vector_type(8)));
typedef _Float16 f16x4 __attribute__((ext_vector_type(4)));
typedef _Float16 f16x2 __attribute__((ext_vector_type(2)));
typedef float f32x4 __attribute__((ext_vector_type(4)));

#define L2E 1.44269504088896f

typedef __attribute__((address_space(1))) void GV;
typedef __attribute__((address_space(3))) void LV;
__device__ __forceinline__ void gl2lds(const void* gp, void* lp) {
    __builtin_amdgcn_global_load_lds((GV*)gp, (LV*)lp, 16, 0, 0);
}

// ---------------- W convert fp32 -> f16 ----------------
__global__ void k_wcvt(const float* __restrict__ w, f16* __restrict__ wh) {
    int i = (blockIdx.x * 256 + threadIdx.x) * 4;
    float4 v = *(const float4*)(w + i);
    f16x4 o = { (f16)v.x, (f16)v.y, (f16)v.z, (f16)v.w };
    *(f16x4*)(wh + i) = o;
}

// ------- depthwise 3x3 conv + transpose [B,C,N]->[B,N,C] + f16 cast -------
__launch_bounds__(256)
__global__ void k_prep(const float* __restrict__ x, const float* __restrict__ wdw,
                       const float* __restrict__ bdw,
                       f16* __restrict__ xt, f16* __restrict__ rbt) {
    int ht = blockIdx.x, ct = blockIdx.y, b = blockIdx.z;
    __shared__ float xs[64 * 129];
    int t = threadIdx.x;
    int h0 = ht * 2;
#pragma unroll
    for (int i = 0; i < 8; ++i) {
        int idx = t + i * 256;
        int cl = idx >> 5, col4 = idx & 31;
        int hh = h0 - 1 + (col4 >> 3);
        int wq = (col4 & 7) * 4;
        float4 v = make_float4(0.f, 0.f, 0.f, 0.f);
        if (hh >= 0 && hh < 32)
            v = *(const float4*)(x + (size_t)(b * 384 + ct * 64 + cl) * 1024 + hh * 32 + wq);
        int base = cl * 129 + col4 * 4;
        xs[base] = v.x; xs[base + 1] = v.y; xs[base + 2] = v.z; xs[base + 3] = v.w;
    }
    __syncthreads();
    int cl = t & 63;
    int c = ct * 64 + cl;
    float wd[9];
#pragma unroll
    for (int k = 0; k < 9; ++k) wd[k] = wdw[c * 9 + k];
    float bd = bdw[c];
    const float* row = &xs[cl * 129];
    int nb = (t >> 6) * 16;
#pragma unroll
    for (int i = 0; i < 16; ++i) {
        int nl = nb + i;
        int hh = nl >> 5, ww = nl & 31;
        int lx = hh + 1;
        float acc = bd;
#pragma unroll
        for (int dh = -1; dh <= 1; ++dh) {
#pragma unroll
            for (int dw = -1; dw <= 1; ++dw) {
                int w2 = ww + dw;
                if (w2 >= 0 && w2 <= 31)
                    acc += wd[(dh + 1) * 3 + (dw + 1)] * row[(lx + dh) * 32 + w2];
            }
        }
        float xc = row[lx * 32 + ww];
        size_t at = ((size_t)(b * 1024) + h0 * 32 + nl) * 384 + c;
        rbt[at] = (f16)acc;
        xt[at] = (f16)xc;
    }
}

// ------- QKV GEMM v2: 256x128 tile, 512 threads (8 waves, 4x2), BK=64 -------
// grid: (bm=4, bn=9, b=16) = 576 blocks. LDS 48 KB static.
__launch_bounds__(512, 2)
__global__ void k_gemm2(const f16* __restrict__ xt, const f16* __restrict__ wh,
                        const float* __restrict__ bias, const f16* __restrict__ rbt,
                        f16* __restrict__ qo, f16* __restrict__ krb, f16* __restrict__ vt) {
    __shared__ f16 As[256 * 64];   // 32 KB
    __shared__ f16 Bs[128 * 64];   // 16 KB
    int bm = blockIdx.x, bn = blockIdx.y, b = blockIdx.z;
    int t = threadIdx.x, lane = t & 63, wv = t >> 6;
    int wm = wv >> 1, wn = wv & 1;        // wm 0..3 (64 rows each), wn 0..1
    f32x4 acc[4][4] = {};
    const char* xbase = (const char*)(xt + (size_t)(b * 1024 + bm * 256) * 384);
    const char* wbase = (const char*)(wh + (size_t)(bn * 128) * 384);
    const bool vmode = (bn >= 6);
    int soffA[4], soffB[2];
#pragma unroll
    for (int i = 0; i < 4; ++i) {
        int idx = i * 512 + t;            // 2048 granules: 256 rows x 8
        int r = idx >> 3, cg = idx & 7;
        soffA[i] = r * 768 + ((cg ^ (r & 7)) << 4);
    }
#pragma unroll
    for (int i = 0; i < 2; ++i) {
        int idx = i * 512 + t;            // 1024 granules: 128 rows x 8
        int r = idx >> 3, cg = idx & 7;
        soffB[i] = r * 768 + ((cg ^ (r & 7)) << 4);
    }
    for (int kc = 0; kc < 6; ++kc) {
        __syncthreads();
#pragma unroll
        for (int i = 0; i < 4; ++i)
            gl2lds(xbase + kc * 128 + soffA[i], (char*)As + (i * 512 + wv * 64) * 16);
#pragma unroll
        for (int i = 0; i < 2; ++i)
            gl2lds(wbase + kc * 128 + soffB[i], (char*)Bs + (i * 512 + wv * 64) * 16);
        __syncthreads();
#pragma unroll
        for (int j = 0; j < 2; ++j) {
            f16x8 af[4], bf[4];
#pragma unroll
            for (int mr = 0; mr < 4; ++mr) {
                int rowi = wm * 64 + mr * 16 + (lane & 15);
                af[mr] = *(const f16x8*)((const char*)As + rowi * 128 +
                         ((j * 64 + (lane >> 4) * 16) ^ ((rowi & 7) << 4)));
            }
#pragma unroll
            for (int nr = 0; nr < 4; ++nr) {
                int rowi = wn * 64 + nr * 16 + (lane & 15);
                bf[nr] = *(const f16x8*)((const char*)Bs + rowi * 128 +
                         ((j * 64 + (lane >> 4) * 16) ^ ((rowi & 7) << 4)));
            }
            __builtin_amdgcn_s_setprio(1);
            if (!vmode) {
#pragma unroll
                for (int mr = 0; mr < 4; ++mr)
#pragma unroll
                    for (int nr = 0; nr < 4; ++nr)
                        acc[mr][nr] = __builtin_amdgcn_mfma_f32_16x16x32_f16(af[mr], bf[nr], acc[mr][nr], 0, 0, 0);
            } else {
#pragma unroll
                for (int mr = 0; mr < 4; ++mr)
#pragma unroll
                    for (int nr = 0; nr < 4; ++nr)
                        acc[mr][nr] = __builtin_amdgcn_mfma_f32_16x16x32_f16(bf[nr], af[mr], acc[mr][nr], 0, 0, 0);
            }
            __builtin_amdgcn_s_setprio(0);
        }
    }
    int o0 = bn * 128;
    if (!vmode) {
#pragma unroll
        for (int nr = 0; nr < 4; ++nr) {
            int o = o0 + wn * 64 + nr * 16 + (lane & 15);
            float bs = bias[o];
#pragma unroll
            for (int mr = 0; mr < 4; ++mr) {
                int n_l = wm * 64 + mr * 16 + ((lane >> 4) << 2);
#pragma unroll
                for (int r = 0; r < 4; ++r) {
                    int n_sp = bm * 256 + n_l + r;
                    size_t at = (size_t)(b * 1024 + n_sp) * 384;
                    float vv = acc[mr][nr][r] + bs;
                    if (o < 384) qo[at + o] = (f16)vv;
                    else krb[at + (o - 384)] = (f16)(vv + (float)rbt[at + (o - 384)]);
                }
            }
        }
    } else {
#pragma unroll
        for (int nr = 0; nr < 4; ++nr) {
#pragma unroll
            for (int mr = 0; mr < 4; ++mr) {
                int n_sp = bm * 256 + wm * 64 + mr * 16 + (lane & 15);
                int o_l = wn * 64 + nr * 16 + ((lane >> 4) << 2);
#pragma unroll
                for (int r = 0; r < 4; ++r) {
                    float vv = acc[mr][nr][r] + bias[o0 + o_l + r];
                    vt[(size_t)(b * 384 + (o0 - 768) + o_l + r) * 1024 + n_sp] = (f16)vv;
                }
            }
        }
    }
}

// ---------------- flash attention v6 = flash3 (79.7us) + V-swizzle fix ----------------
// grid: (qt=16, b=16), 256 threads (4 waves, wave owns 16 q-rows). KVBLK=32.
// Ks [32 kv][384 c] f16 (24 KB) + Vs [384 c][32 kv] f16 (24 KB) = 48 KB static.
__launch_bounds__(256, 1)
__global__ void k_flash6(const f16* __restrict__ q, const f16* __restrict__ krb,
                         const f16* __restrict__ vt, float* __restrict__ out) {
    __shared__ char smem[49152];
    char* Ks = smem;
    char* Vs = smem + 24576;
    int qt = blockIdx.x, b = blockIdx.y;
    int t = threadIdx.x, lane = t & 63, wv = t >> 6;
    int g = lane >> 4, ln = lane & 15;
    int n0 = qt * 64;

    // Q as B-fragment (col=q=ln, k = g*8+e per 32-c chunk)
    f16x8 qf[12];
    {
        const f16* qb = q + (size_t)(b * 1024 + n0 + wv * 16 + ln) * 384 + g * 8;
#pragma unroll
        for (int kc = 0; kc < 12; ++kc) qf[kc] = *(const f16x8*)(qb + kc * 32);
    }

    // staging source offsets (pre-swizzled global source; linear LDS dest)
    int koff[6], voff[6];
#pragma unroll
    for (int i = 0; i < 6; ++i) {
        int idx = i * 256 + t;                         // 1536 granules
        int r = idx / 48, c = idx - r * 48;            // K: 32 rows x 48 granules
        koff[i] = r * 768 + ((c ^ (r & 7)) << 4);
        int vr = idx >> 2, vc = idx & 3;               // V: 384 rows x 4 granules
        int sv = (vr + (vr >> 2)) & 3;                 // uniform 2-way swizzle
        voff[i] = vr * 2048 + ((vc ^ sv) << 4);
    }
    const char* kbase = (const char*)(krb + (size_t)b * 1024 * 384);
    const char* vbase = (const char*)(vt + (size_t)b * 384 * 1024);

    // prologue: stage K[0]
#pragma unroll
    for (int i = 0; i < 6; ++i)
        gl2lds(kbase + koff[i], Ks + (i * 256 + wv * 64) * 16);

    f32x4 oa[24];
#pragma unroll
    for (int i = 0; i < 24; ++i) oa[i] = (f32x4){0.f, 0.f, 0.f, 0.f};
    float m_run = -1e30f, l_run = 0.f;
    int src0 = 2 * (g & 1) * 16 + ln, src1 = src0 + 16;
    bool gh = (g >= 2);

    for (int kt = 0; kt < 32; ++kt) {
        __syncthreads();               // K[kt] landed; Vs free
#pragma unroll
        for (int i = 0; i < 6; ++i)    // async stage V[kt] under QK
            gl2lds(vbase + kt * 64 + voff[i], Vs + (i * 256 + wv * 64) * 16);

        // QK^T swapped: S^T[kv][q], kv = nr*16 + g*4 + r, q = ln
        f32x4 st[2] = {};
        __builtin_amdgcn_s_setprio(1);
#pragma unroll
        for (int kc = 0; kc < 12; ++kc) {
#pragma unroll
            for (int nr = 0; nr < 2; ++nr) {
                int kvr = nr * 16 + ln;
                f16x8 kf = *(const f16x8*)(Ks + kvr * 768 +
                            ((kc * 64 + g * 16) ^ ((kvr & 7) << 4)));
                st[nr] = __builtin_amdgcn_mfma_f32_16x16x32_f16(kf, qf[kc], st[nr], 0, 0, 0);
            }
        }
        __builtin_amdgcn_s_setprio(0);

        // register online softmax (per-lane q = ln)
        float mx = st[0][0];
#pragma unroll
        for (int nr = 0; nr < 2; ++nr)
#pragma unroll
            for (int r = 0; r < 4; ++r) mx = fmaxf(mx, st[nr][r]);
        mx = fmaxf(mx, __shfl_xor(mx, 16));
        mx = fmaxf(mx, __shfl_xor(mx, 32));
        float mn = fmaxf(m_run, mx);
        float sc = exp2f((m_run - mn) * L2E);
        m_run = mn;
        float ls = 0.f;
        float pv[2][4];
#pragma unroll
        for (int nr = 0; nr < 2; ++nr)
#pragma unroll
            for (int r = 0; r < 4; ++r) {
                float p = exp2f((st[nr][r] - mn) * L2E);
                pv[nr][r] = p;
                ls += p;
            }
        ls += __shfl_xor(ls, 16);
        ls += __shfl_xor(ls, 32);
        l_run = l_run * sc + ls;
#pragma unroll
        for (int i = 0; i < 24; ++i) oa[i] *= sc;

        // pack P^T to f16 pairs, shuffle into PV B-fragment (k=kv local, col=q)
        int pk[4];
#pragma unroll
        for (int nr = 0; nr < 2; ++nr)
#pragma unroll
            for (int hh = 0; hh < 2; ++hh) {
                f16x2 w2 = { (f16)pv[nr][2 * hh], (f16)pv[nr][2 * hh + 1] };
                pk[nr * 2 + hh] = __builtin_bit_cast(int, w2);
            }
        f16x8 pb;
        {
            int a0 = __shfl(pk[0], src0);
            int a1 = __shfl(pk[1], src0);
            int a2 = __shfl(pk[2], src0);
            int a3 = __shfl(pk[3], src0);
            int b0 = __shfl(pk[0], src1);
            int b1 = __shfl(pk[1], src1);
            int b2 = __shfl(pk[2], src1);
            int b3 = __shfl(pk[3], src1);
            union { int w[4]; f16x8 v; } u;
            u.w[0] = gh ? a2 : a0;
            u.w[1] = gh ? a3 : a1;
            u.w[2] = gh ? b2 : b0;
            u.w[3] = gh ? b3 : b1;
            pb = u.v;
        }

        __syncthreads();               // V[kt] landed; Ks consumed
        if (kt < 31) {                 // async stage K[kt+1] under PV
#pragma unroll
            for (int i = 0; i < 6; ++i)
                gl2lds(kbase + (kt + 1) * 24576 + koff[i], Ks + (i * 256 + wv * 64) * 16);
        }

        // PV: O^T[c][q] += V^T x P^T (K=32, one MFMA per c-block; 2-way V reads)
        __builtin_amdgcn_s_setprio(1);
#pragma unroll
        for (int nr2 = 0; nr2 < 24; ++nr2) {
            int cr = nr2 * 16 + ln;
            int sv = (cr + (cr >> 2)) & 3;
            f16x8 vf = *(const f16x8*)(Vs + cr * 64 + ((g ^ sv) << 4));
            oa[nr2] = __builtin_amdgcn_mfma_f32_16x16x32_f16(vf, pb, oa[nr2], 0, 0, 0);
        }
        __builtin_amdgcn_s_setprio(0);
    }

    // epilogue: O^T/l -> out[b][c][n]
    float inv = 1.0f / l_run;
#pragma unroll
    for (int nr2 = 0; nr2 < 24; ++nr2) {
#pragma unroll
        for (int r = 0; r < 4; ++r) {
            int c = nr2 * 16 + g * 4 + r;
            out[(size_t)(b * 384 + c) * 1024 + n0 + wv * 16 + ln] = oa[nr2][r] * inv;
        }
    }
}

extern "C" void kernel_launch(void* const* d_in, const int* in_sizes, int n_in,
                              void* d_out, int out_size, void* d_ws, size_t ws_size,
                              hipStream_t stream) {
    const float* x     = (const float*)d_in[0];
    const float* w_qkv = (const float*)d_in[1];
    const float* b_qkv = (const float*)d_in[2];
    const float* w_dw  = (const float*)d_in[3];
    const float* b_dw  = (const float*)d_in[4];
    float* out = (float*)d_out;
    char* ws = (char*)d_ws;
    const size_t SZ = (size_t)16 * 1024 * 384 * 2;
    f16* xt  = (f16*)(ws);
    f16* rbt = (f16*)(ws + SZ);
    f16* qo  = (f16*)(ws + 2 * SZ);
    f16* krb = (f16*)(ws + 3 * SZ);
    f16* vt  = (f16*)(ws + 4 * SZ);
    f16* wh  = (f16*)(ws + 5 * SZ);

    k_wcvt<<<432, 256, 0, stream>>>(w_qkv, wh);
    k_prep<<<dim3(16, 6, 16), 256, 0, stream>>>(x, w_dw, b_dw, xt, rbt);
    k_gemm2<<<dim3(4, 9, 16), 512, 0, stream>>>(xt, wh, b_qkv, rbt, qo, krb, vt);
    k_flash6<<<dim3(16, 16), 256, 0, stream>>>(qo, krb, vt, out);
}